// Round 9
// baseline (256.404 us; speedup 1.0000x reference)
//
#include <hip/hip_runtime.h>
#include <math.h>

// CRDLoss on MI355X.
// Phase 0: convert W_s/W_t -> fp16 in ws (1 MB, L2-resident thereafter).
// Phase 1: embed GEMM 8192x2048x128 + bias + L2-norm -> fp16 embeddings.
//          R9: A (X) streams global->register directly (no LDS, no barrier on
//          the heavy stream; per-wave prefetch 1 iter ahead). Only B (W16,
//          L2-hot) goes through a double-buffered LDS tile. R6/R7/R8 all
//          plateaued at ~56us because X loads were only in flight during the
//          short MFMA window between barriers (delivered BW 2.4 TB/s).
// Phase 2: 8192x8192 similarity via f16 MFMA, fused exp/log epilogue (proven).
// Phase 3: reduce 4096 partials -> out[0] = -(sum)/B.

typedef _Float16 half_t;
typedef half_t halfx4 __attribute__((ext_vector_type(4)));
typedef half_t halfx8 __attribute__((ext_vector_type(8)));
typedef float f32x4 __attribute__((ext_vector_type(4)));

#define B_TOT   8192
#define K_EMB   2048
#define F_DIM   128
#define INV_T   14.285714285714286f   // 1/0.07
#define EPS_C   0.97f
#define LOG_EPS (-0.030459207485f)    // ln(0.97)

// ---------------------------------------------------------------------------
// W fp32 -> fp16.  grid = (256, 2); block = 256; one float4 per thread.
// ---------------------------------------------------------------------------
__global__ __launch_bounds__(256) void cvt_w_kernel(
    const float* __restrict__ Ws, const float* __restrict__ Wt,
    half_t* __restrict__ Ws16, half_t* __restrict__ Wt16)
{
    const float* src = blockIdx.y ? Wt : Ws;
    half_t* dst = blockIdx.y ? Wt16 : Ws16;
    int pos4 = blockIdx.x * 256 + threadIdx.x;      // 0..65535
    float4 v = *(const float4*)(src + (size_t)pos4 * 4);
    halfx4 h4 = {(half_t)v.x, (half_t)v.y, (half_t)v.z, (half_t)v.w};
    *(halfx4*)(dst + (size_t)pos4 * 4) = h4;
}

// ---------------------------------------------------------------------------
// Embed: 16-row tile x 128 cols, BK=64.
// A: global->register fragments per wave (prefetch depth 1, no barrier dep).
// B: W16 via double-buffered XOR-swizzled LDS (16 KB/buffer).
// grid = (512, 2); block = 256; 4 waves, wave w owns cols w*32..w*32+31.
// ---------------------------------------------------------------------------
__global__ __launch_bounds__(256) void embed_kernel(
    const float* __restrict__ Xs, const float* __restrict__ Xt,
    const half_t* __restrict__ Ws16, const half_t* __restrict__ Wt16,
    const float* __restrict__ bs, const float* __restrict__ bt,
    half_t* __restrict__ outs, half_t* __restrict__ outt)
{
    const float* X; const half_t* W16; const float* bias; half_t* out;
    if (blockIdx.y == 0) { X = Xs; W16 = Ws16; bias = bs; out = outs; }
    else                 { X = Xt; W16 = Wt16; bias = bt; out = outt; }

    // B: 128 rows x 8 chunks (16B) per BK=64, phys = row*8 + (c ^ (row&7))
    __shared__ uint4 Bs4[2][128 * 8];   // 2 x 16 KB
    __shared__ float biasS[128];
    __shared__ float redS[16][4];
    __shared__ float invS[16];

    const int tid = threadIdx.x;
    const int r0  = blockIdx.x * 16;
    if (tid < 128) biasS[tid] = bias[tid];

    const int lane = tid & 63;
    const int w    = tid >> 6;           // wave -> cols w*32
    const int l16  = lane & 15, lhi = lane >> 4;

    // per-lane A row base: lane l16 owns output row r0+l16; k-slice from lhi
    const float* Arow = X + (size_t)(r0 + l16) * K_EMB + lhi * 8;

    // B staging coords: 1024 chunks / 256 threads = 4 each
    const int brow = tid >> 3;           // rows 0..31 (+i*32)
    const int bc   = tid & 7;

    f32x4 acc[2];
    acc[0] = f32x4{0.f, 0.f, 0.f, 0.f};
    acc[1] = f32x4{0.f, 0.f, 0.f, 0.f};

    float4 a0[2], a1[2];   // current iter A frags: [kk][lo/hi]
    float4 p0[2], p1[2];   // prefetched next iter
    uint4  nb[4];

    // prologue: A(it=0) and B(it=0) into buffer 0
    a0[0] = *(const float4*)(Arow);
    a1[0] = *(const float4*)(Arow + 4);
    a0[1] = *(const float4*)(Arow + 32);
    a1[1] = *(const float4*)(Arow + 36);
#pragma unroll
    for (int i = 0; i < 4; ++i) {
        int row = brow + i * 32;
        Bs4[0][row * 8 + (bc ^ (row & 7))] =
            *(const uint4*)(W16 + (size_t)row * K_EMB + bc * 8);
    }
    __syncthreads();

    for (int it = 0; it < 32; ++it) {
        const int cur = it & 1;
        if (it < 31) {
            const int kn = (it + 1) * 64;
            p0[0] = *(const float4*)(Arow + kn);
            p1[0] = *(const float4*)(Arow + kn + 4);
            p0[1] = *(const float4*)(Arow + kn + 32);
            p1[1] = *(const float4*)(Arow + kn + 36);
#pragma unroll
            for (int i = 0; i < 4; ++i) {
                int row = brow + i * 32;
                nb[i] = *(const uint4*)(W16 + (size_t)row * K_EMB + kn + bc * 8);
            }
        }
#pragma unroll
        for (int kk = 0; kk < 2; ++kk) {
            halfx8 a = {(half_t)a0[kk].x, (half_t)a0[kk].y, (half_t)a0[kk].z, (half_t)a0[kk].w,
                        (half_t)a1[kk].x, (half_t)a1[kk].y, (half_t)a1[kk].z, (half_t)a1[kk].w};
#pragma unroll
            for (int in = 0; in < 2; ++in) {
                int row = w * 32 + in * 16 + l16;
                halfx8 b = *(const halfx8*)&Bs4[cur][row * 8 + ((kk * 4 + lhi) ^ (l16 & 7))];
                acc[in] = __builtin_amdgcn_mfma_f32_16x16x32_f16(a, b, acc[in], 0, 0, 0);
            }
        }
        if (it < 31) {
            const int nxt = cur ^ 1;
#pragma unroll
            for (int i = 0; i < 4; ++i) {
                int row = brow + i * 32;
                Bs4[nxt][row * 8 + (bc ^ (row & 7))] = nb[i];
            }
            a0[0] = p0[0]; a1[0] = p1[0]; a0[1] = p0[1]; a1[1] = p1[1];
        }
        __syncthreads();
    }

    // epilogue: +bias, row sum-of-squares (this wave's 32 cols), normalize
    float h[2][4];
    float psum[4];
#pragma unroll
    for (int reg = 0; reg < 4; ++reg) {
        float p = 0.f;
#pragma unroll
        for (int in = 0; in < 2; ++in) {
            int col = w * 32 + in * 16 + l16;
            float v = acc[in][reg] + biasS[col];
            h[in][reg] = v;
            p += v * v;
        }
        p += __shfl_xor(p, 1);
        p += __shfl_xor(p, 2);
        p += __shfl_xor(p, 4);
        p += __shfl_xor(p, 8);
        psum[reg] = p;
    }
    if (l16 == 0)
#pragma unroll
        for (int reg = 0; reg < 4; ++reg)
            redS[lhi * 4 + reg][w] = psum[reg];
    __syncthreads();
    if (tid < 16)
        invS[tid] = rsqrtf(redS[tid][0] + redS[tid][1] + redS[tid][2] + redS[tid][3]);
    __syncthreads();

#pragma unroll
    for (int in = 0; in < 2; ++in)
#pragma unroll
        for (int reg = 0; reg < 4; ++reg) {
            int row = lhi * 4 + reg;
            int col = w * 32 + in * 16 + l16;
            out[(size_t)(r0 + row) * F_DIM + col] = (half_t)(h[in][reg] * invS[row]);
        }
}

// ---------------------------------------------------------------------------
// Loss: 128x128 tile of fs·ft^T, K=128 in two 64-wide LDS chunks (33 KB LDS).
// grid = (64, 64); block = 256.  (unchanged, proven)
// ---------------------------------------------------------------------------
__global__ __launch_bounds__(256) void loss_kernel(
    const half_t* __restrict__ FS, const half_t* __restrict__ FT,
    const int* __restrict__ y, double* __restrict__ partials)
{
    __shared__ uint4 As4[128 * 8];   // 16 KB
    __shared__ uint4 Bs4[128 * 8];   // 16 KB
    __shared__ int   yrl[128], ycl[128];
    __shared__ float wsum[4];

    const int tid = threadIdx.x;
    const int i0  = blockIdx.x * 128;
    const int j0  = blockIdx.y * 128;

    if (tid < 128) yrl[tid] = y[i0 + tid];
    else           ycl[tid - 128] = y[j0 + tid - 128];

    const int lane = tid & 63;
    const int w    = tid >> 6;
    const int wm   = w >> 1, wn = w & 1;
    const int l16  = lane & 15, lhi = lane >> 4;

#pragma unroll
    for (int i = 0; i < 4; ++i) {
        int f = tid + i * 256;
        int row = f >> 3, c = f & 7;
        As4[row * 8 + (c ^ (row & 7))] = *(const uint4*)(FS + (size_t)(i0 + row) * F_DIM + c * 8);
    }
#pragma unroll
    for (int i = 0; i < 4; ++i) {
        int f = tid + i * 256;
        int row = f >> 3, c = f & 7;
        Bs4[row * 8 + (c ^ (row & 7))] = *(const uint4*)(FT + (size_t)(j0 + row) * F_DIM + c * 8);
    }
    __syncthreads();

    f32x4 acc[4][4];
    for (int im = 0; im < 4; ++im)
        for (int in = 0; in < 4; ++in)
            acc[im][in] = f32x4{0.f, 0.f, 0.f, 0.f};

    for (int kc = 0; kc < 2; ++kc) {
#pragma unroll
        for (int kk = 0; kk < 2; ++kk) {
            halfx8 a[4], b[4];
#pragma unroll
            for (int im = 0; im < 4; ++im) {
                int r = wm * 64 + im * 16 + l16;
                a[im] = *(const halfx8*)&As4[r * 8 + ((kk * 4 + lhi) ^ (r & 7))];
            }
#pragma unroll
            for (int in = 0; in < 4; ++in) {
                int r = wn * 64 + in * 16 + l16;
                b[in] = *(const halfx8*)&Bs4[r * 8 + ((kk * 4 + lhi) ^ (r & 7))];
            }
#pragma unroll
            for (int im = 0; im < 4; ++im)
#pragma unroll
                for (int in = 0; in < 4; ++in)
                    acc[im][in] = __builtin_amdgcn_mfma_f32_16x16x32_f16(
                        a[im], b[in], acc[im][in], 0, 0, 0);
        }
        if (kc == 0) {
            __syncthreads();
#pragma unroll
            for (int i = 0; i < 4; ++i) {
                int f = tid + i * 256;
                int row = f >> 3, c = f & 7;
                As4[row * 8 + (c ^ (row & 7))] =
                    *(const uint4*)(FS + (size_t)(i0 + row) * F_DIM + 64 + c * 8);
            }
#pragma unroll
            for (int i = 0; i < 4; ++i) {
                int f = tid + i * 256;
                int row = f >> 3, c = f & 7;
                Bs4[row * 8 + (c ^ (row & 7))] =
                    *(const uint4*)(FT + (size_t)(j0 + row) * F_DIM + 64 + c * 8);
            }
            __syncthreads();
        }
    }

    float local = 0.f;
    for (int im = 0; im < 4; ++im) {
        for (int reg = 0; reg < 4; ++reg) {
            int il = wm * 64 + im * 16 + lhi * 4 + reg;
            int yi = yrl[il];
            int gi = i0 + il;
            for (int in = 0; in < 4; ++in) {
                int jl = wn * 64 + in * 16 + l16;
                float s  = acc[im][in][reg];
                float sT = s * INV_T;
                float e  = __expf(sT);
                float l  = __logf(e + EPS_C);
                float term = (yi == ycl[jl]) ? (sT - l) : (LOG_EPS - l);
                if (gi != (j0 + jl)) local += term;
            }
        }
    }
    for (int m = 1; m < 64; m <<= 1) local += __shfl_xor(local, m);
    if (lane == 0) wsum[w] = local;
    __syncthreads();
    if (tid == 0)
        partials[blockIdx.y * gridDim.x + blockIdx.x] =
            ((double)wsum[0] + (double)wsum[1]) + ((double)wsum[2] + (double)wsum[3]);
}

// ---------------------------------------------------------------------------
__global__ __launch_bounds__(256) void finalize_kernel(
    const double* __restrict__ partials, float* __restrict__ out)
{
    __shared__ double sh[4];
    double loc = 0.0;
    for (int i = threadIdx.x; i < 4096; i += 256) loc += partials[i];
    for (int m = 1; m < 64; m <<= 1) loc += __shfl_xor(loc, m);
    int lane = threadIdx.x & 63, w = threadIdx.x >> 6;
    if (lane == 0) sh[w] = loc;
    __syncthreads();
    if (threadIdx.x == 0)
        out[0] = (float)(-(sh[0] + sh[1] + sh[2] + sh[3]) / (double)B_TOT);
}

// ---------------------------------------------------------------------------
extern "C" void kernel_launch(void* const* d_in, const int* in_sizes, int n_in,
                              void* d_out, int out_size, void* d_ws, size_t ws_size,
                              hipStream_t stream)
{
    // ws layout: [partials 32KB | pad->64KB | fs 2MB | ft 2MB | Ws16 512KB | Wt16 512KB]
    const size_t WS_NEEDED = (64 << 10) + (4 << 20) + (1 << 20);
    if (ws_size < WS_NEEDED) return;   // readable failure instead of OOB fault

    const float* f_s = (const float*)d_in[0];
    const float* f_t = (const float*)d_in[1];
    const int*   y   = (const int*)d_in[2];
    const float* W_s = (const float*)d_in[3];
    const float* b_s = (const float*)d_in[4];
    const float* W_t = (const float*)d_in[5];
    const float* b_t = (const float*)d_in[6];
    float* out = (float*)d_out;

    char* ws = (char*)d_ws;
    double* partials = (double*)ws;                               // 32 KB
    half_t* fs   = (half_t*)(ws + (64 << 10));                    // 2 MB
    half_t* ft   = (half_t*)(ws + (64 << 10) + (2 << 20));        // 2 MB
    half_t* Ws16 = (half_t*)(ws + (64 << 10) + (4 << 20));        // 512 KB
    half_t* Wt16 = (half_t*)(ws + (64 << 10) + (4 << 20) + (512 << 10));

    cvt_w_kernel<<<dim3(256, 2), 256, 0, stream>>>(W_s, W_t, Ws16, Wt16);
    embed_kernel<<<dim3(512, 2), 256, 0, stream>>>(f_s, f_t, Ws16, Wt16, b_s, b_t, fs, ft);
    loss_kernel<<<dim3(64, 64), 256, 0, stream>>>(fs, ft, y, partials);
    finalize_kernel<<<1, 256, 0, stream>>>(partials, out);
    (void)in_sizes; (void)n_in; (void)out_size;
}

// Round 10
// 234.963 us; speedup vs baseline: 1.0913x; 1.0913x over previous
//
#include <hip/hip_runtime.h>
#include <math.h>

// CRDLoss on MI355X.
// Phase 0: convert W_s/W_t -> fp16 in ws (1 MB, L2-resident thereafter).
// Phase 1: embed GEMM 8192x2048x128 + bias + L2-norm -> fp16 embeddings.
//          R10: register-resident W (per wave: 2 col-groups x 16 k-chunks =
//          128 VGPRs, reloaded per 512-wide K-phase), fp32 accumulator panel
//          in LDS across phases, X streamed ONCE coalesced + double-buffered.
//          R6-R8 plateaued ~56us: each block re-read all of W16 every iter
//          (512 MB L2 traffic vs 134 MB X) through a barrier-locked pipe.
//          R9 (reg-direct A frags) regressed: scattered 64B segments + 4x
//          wave duplication.
// Phase 2: 8192x8192 similarity via f16 MFMA, fused exp/log epilogue (proven).
// Phase 3: reduce 4096 partials -> out[0] = -(sum)/B.

typedef _Float16 half_t;
typedef half_t halfx4 __attribute__((ext_vector_type(4)));
typedef half_t halfx8 __attribute__((ext_vector_type(8)));
typedef float f32x4 __attribute__((ext_vector_type(4)));

#define B_TOT   8192
#define K_EMB   2048
#define F_DIM   128
#define INV_T   14.285714285714286f   // 1/0.07
#define EPS_C   0.97f
#define LOG_EPS (-0.030459207485f)    // ln(0.97)

// ---------------------------------------------------------------------------
// W fp32 -> fp16.  grid = (256, 2); block = 256; one float4 per thread.
// ---------------------------------------------------------------------------
__global__ __launch_bounds__(256) void cvt_w_kernel(
    const float* __restrict__ Ws, const float* __restrict__ Wt,
    half_t* __restrict__ Ws16, half_t* __restrict__ Wt16)
{
    const float* src = blockIdx.y ? Wt : Ws;
    half_t* dst = blockIdx.y ? Wt16 : Ws16;
    int pos4 = blockIdx.x * 256 + threadIdx.x;      // 0..65535
    float4 v = *(const float4*)(src + (size_t)pos4 * 4);
    halfx4 h4 = {(half_t)v.x, (half_t)v.y, (half_t)v.z, (half_t)v.w};
    *(halfx4*)(dst + (size_t)pos4 * 4) = h4;
}

// ---------------------------------------------------------------------------
// Embed: 32-row panel x 128 cols, K in 4 register-resident W-phases (512 each).
// Per (phase, 16-row chunk): X staged fp32->fp16 into double-buffered swizzled
// LDS; 32 MFMAs/wave; fp32 acc panel RMW in LDS. Epilogue: bias+L2norm+store.
// grid = (256, 2); block = 256; 4 waves, wave w owns cols w*32..w*32+31.
// ---------------------------------------------------------------------------
__global__ __launch_bounds__(256) void embed_kernel(
    const float* __restrict__ Xs, const float* __restrict__ Xt,
    const half_t* __restrict__ Ws16, const half_t* __restrict__ Wt16,
    const float* __restrict__ bs, const float* __restrict__ bt,
    half_t* __restrict__ outs, half_t* __restrict__ outt)
{
    const float* X; const half_t* W16; const float* bias; half_t* out;
    if (blockIdx.y == 0) { X = Xs; W16 = Ws16; bias = bs; out = outs; }
    else                 { X = Xt; W16 = Wt16; bias = bt; out = outt; }

    // A: 16 rows x 64 16B-chunks (512 k halves), phys = row*64 + (c16 ^ row)
    __shared__ uint4 Abuf[2][16 * 64];   // 2 x 16 KB
    __shared__ float accS[32][132];      // 16.9 KB, pad 132 -> <=2-way banks
    __shared__ float biasS[128];

    const int tid = threadIdx.x;
    const int r0  = blockIdx.x * 32;

    for (int i = tid; i < 32 * 132; i += 256) ((float*)accS)[i] = 0.f;
    if (tid < 128) biasS[tid] = bias[tid];

    const int lane = tid & 63;
    const int w    = tid >> 6;           // wave -> cols w*32
    const int l16  = lane & 15, lhi = lane >> 4;

    float4 av[8];
    halfx8 Wf[2][16];

    // ---- prologue: load+store A(it=0) ----
    {
        const float* base = X + (size_t)r0 * K_EMB;   // ks=0, rc=0
#pragma unroll
        for (int i = 0; i < 8; ++i) {
            int f = tid + i * 256;
            av[i] = *(const float4*)(base + (size_t)(f >> 7) * K_EMB + (f & 127) * 4);
        }
#pragma unroll
        for (int i = 0; i < 8; ++i) {
            int f = tid + i * 256;
            int row = f >> 7, c = f & 127;
            int phys = row * 64 + ((c >> 1) ^ row);
            halfx4 h = {(half_t)av[i].x, (half_t)av[i].y, (half_t)av[i].z, (half_t)av[i].w};
            *(halfx4*)((half_t*)&Abuf[0][phys] + (c & 1) * 4) = h;
        }
    }
    __syncthreads();   // A(0) visible, accS zeroed

    for (int ks = 0; ks < 4; ++ks) {
        // register-resident W slice for this phase (L2-hot after cvt)
#pragma unroll
        for (int g = 0; g < 2; ++g)
#pragma unroll
            for (int j = 0; j < 16; ++j)
                Wf[g][j] = *(const halfx8*)(W16 +
                    (size_t)((w * 2 + g) * 16 + l16) * K_EMB + ks * 512 + j * 32 + lhi * 8);

#pragma unroll
        for (int rc = 0; rc < 2; ++rc) {
            const int it  = ks * 2 + rc;
            const int cur = it & 1;
            if (it < 7) {   // prefetch A(it+1) into registers
                const int ksn = (it + 1) >> 1, rcn = (it + 1) & 1;
                const float* base = X + (size_t)(r0 + rcn * 16) * K_EMB + ksn * 512;
#pragma unroll
                for (int i = 0; i < 8; ++i) {
                    int f = tid + i * 256;
                    av[i] = *(const float4*)(base + (size_t)(f >> 7) * K_EMB + (f & 127) * 4);
                }
            }
            f32x4 acc0 = f32x4{0.f, 0.f, 0.f, 0.f};
            f32x4 acc1 = f32x4{0.f, 0.f, 0.f, 0.f};
#pragma unroll
            for (int j = 0; j < 16; ++j) {
                halfx8 a = *(const halfx8*)&Abuf[cur][l16 * 64 + ((j * 4 + lhi) ^ l16)];
                acc0 = __builtin_amdgcn_mfma_f32_16x16x32_f16(a, Wf[0][j], acc0, 0, 0, 0);
                acc1 = __builtin_amdgcn_mfma_f32_16x16x32_f16(a, Wf[1][j], acc1, 0, 0, 0);
            }
            // accumulate into LDS panel (wave-private columns -> no races)
#pragma unroll
            for (int reg = 0; reg < 4; ++reg) {
                int m = rc * 16 + lhi * 4 + reg;
                accS[m][(w * 2 + 0) * 16 + l16] += acc0[reg];
                accS[m][(w * 2 + 1) * 16 + l16] += acc1[reg];
            }
            if (it < 7) {   // convert + store prefetched A into other buffer
                const int nxt = cur ^ 1;
#pragma unroll
                for (int i = 0; i < 8; ++i) {
                    int f = tid + i * 256;
                    int row = f >> 7, c = f & 127;
                    int phys = row * 64 + ((c >> 1) ^ row);
                    halfx4 h = {(half_t)av[i].x, (half_t)av[i].y, (half_t)av[i].z, (half_t)av[i].w};
                    *(halfx4*)((half_t*)&Abuf[nxt][phys] + (c & 1) * 4) = h;
                }
            }
            __syncthreads();
        }
    }

    // ---- epilogue: bias, row L2-norm, fp16 store.  thread -> (row, col-oct)
    {
        const int r = tid >> 3, oct = tid & 7;
        float vals[16];
        float s = 0.f;
#pragma unroll
        for (int q = 0; q < 16; ++q) {
            float v = accS[r][oct * 16 + q] + biasS[oct * 16 + q];
            vals[q] = v;
            s += v * v;
        }
        s += __shfl_xor(s, 1);
        s += __shfl_xor(s, 2);
        s += __shfl_xor(s, 4);
        const float inv = rsqrtf(s);
        halfx8 o0, o1;
#pragma unroll
        for (int q = 0; q < 8; ++q) { o0[q] = (half_t)(vals[q] * inv); o1[q] = (half_t)(vals[q + 8] * inv); }
        half_t* dst = out + (size_t)(r0 + r) * F_DIM + oct * 16;
        *(halfx8*)dst = o0;
        *(halfx8*)(dst + 8) = o1;
    }
}

// ---------------------------------------------------------------------------
// Loss: 128x128 tile of fs·ft^T, K=128 in two 64-wide LDS chunks (33 KB LDS).
// grid = (64, 64); block = 256.  (unchanged, proven)
// ---------------------------------------------------------------------------
__global__ __launch_bounds__(256) void loss_kernel(
    const half_t* __restrict__ FS, const half_t* __restrict__ FT,
    const int* __restrict__ y, double* __restrict__ partials)
{
    __shared__ uint4 As4[128 * 8];   // 16 KB
    __shared__ uint4 Bs4[128 * 8];   // 16 KB
    __shared__ int   yrl[128], ycl[128];
    __shared__ float wsum[4];

    const int tid = threadIdx.x;
    const int i0  = blockIdx.x * 128;
    const int j0  = blockIdx.y * 128;

    if (tid < 128) yrl[tid] = y[i0 + tid];
    else           ycl[tid - 128] = y[j0 + tid - 128];

    const int lane = tid & 63;
    const int w    = tid >> 6;
    const int wm   = w >> 1, wn = w & 1;
    const int l16  = lane & 15, lhi = lane >> 4;

#pragma unroll
    for (int i = 0; i < 4; ++i) {
        int f = tid + i * 256;
        int row = f >> 3, c = f & 7;
        As4[row * 8 + (c ^ (row & 7))] = *(const uint4*)(FS + (size_t)(i0 + row) * F_DIM + c * 8);
    }
#pragma unroll
    for (int i = 0; i < 4; ++i) {
        int f = tid + i * 256;
        int row = f >> 3, c = f & 7;
        Bs4[row * 8 + (c ^ (row & 7))] = *(const uint4*)(FT + (size_t)(j0 + row) * F_DIM + c * 8);
    }
    __syncthreads();

    f32x4 acc[4][4];
    for (int im = 0; im < 4; ++im)
        for (int in = 0; in < 4; ++in)
            acc[im][in] = f32x4{0.f, 0.f, 0.f, 0.f};

    for (int kc = 0; kc < 2; ++kc) {
#pragma unroll
        for (int kk = 0; kk < 2; ++kk) {
            halfx8 a[4], b[4];
#pragma unroll
            for (int im = 0; im < 4; ++im) {
                int r = wm * 64 + im * 16 + l16;
                a[im] = *(const halfx8*)&As4[r * 8 + ((kk * 4 + lhi) ^ (r & 7))];
            }
#pragma unroll
            for (int in = 0; in < 4; ++in) {
                int r = wn * 64 + in * 16 + l16;
                b[in] = *(const halfx8*)&Bs4[r * 8 + ((kk * 4 + lhi) ^ (r & 7))];
            }
#pragma unroll
            for (int im = 0; im < 4; ++im)
#pragma unroll
                for (int in = 0; in < 4; ++in)
                    acc[im][in] = __builtin_amdgcn_mfma_f32_16x16x32_f16(
                        a[im], b[in], acc[im][in], 0, 0, 0);
        }
        if (kc == 0) {
            __syncthreads();
#pragma unroll
            for (int i = 0; i < 4; ++i) {
                int f = tid + i * 256;
                int row = f >> 3, c = f & 7;
                As4[row * 8 + (c ^ (row & 7))] =
                    *(const uint4*)(FS + (size_t)(i0 + row) * F_DIM + 64 + c * 8);
            }
#pragma unroll
            for (int i = 0; i < 4; ++i) {
                int f = tid + i * 256;
                int row = f >> 3, c = f & 7;
                Bs4[row * 8 + (c ^ (row & 7))] =
                    *(const uint4*)(FT + (size_t)(j0 + row) * F_DIM + 64 + c * 8);
            }
            __syncthreads();
        }
    }

    float local = 0.f;
    for (int im = 0; im < 4; ++im) {
        for (int reg = 0; reg < 4; ++reg) {
            int il = wm * 64 + im * 16 + lhi * 4 + reg;
            int yi = yrl[il];
            int gi = i0 + il;
            for (int in = 0; in < 4; ++in) {
                int jl = wn * 64 + in * 16 + l16;
                float s  = acc[im][in][reg];
                float sT = s * INV_T;
                float e  = __expf(sT);
                float l  = __logf(e + EPS_C);
                float term = (yi == ycl[jl]) ? (sT - l) : (LOG_EPS - l);
                if (gi != (j0 + jl)) local += term;
            }
        }
    }
    for (int m = 1; m < 64; m <<= 1) local += __shfl_xor(local, m);
    if (lane == 0) wsum[w] = local;
    __syncthreads();
    if (tid == 0)
        partials[blockIdx.y * gridDim.x + blockIdx.x] =
            ((double)wsum[0] + (double)wsum[1]) + ((double)wsum[2] + (double)wsum[3]);
}

// ---------------------------------------------------------------------------
__global__ __launch_bounds__(256) void finalize_kernel(
    const double* __restrict__ partials, float* __restrict__ out)
{
    __shared__ double sh[4];
    double loc = 0.0;
    for (int i = threadIdx.x; i < 4096; i += 256) loc += partials[i];
    for (int m = 1; m < 64; m <<= 1) loc += __shfl_xor(loc, m);
    int lane = threadIdx.x & 63, w = threadIdx.x >> 6;
    if (lane == 0) sh[w] = loc;
    __syncthreads();
    if (threadIdx.x == 0)
        out[0] = (float)(-(sh[0] + sh[1] + sh[2] + sh[3]) / (double)B_TOT);
}

// ---------------------------------------------------------------------------
extern "C" void kernel_launch(void* const* d_in, const int* in_sizes, int n_in,
                              void* d_out, int out_size, void* d_ws, size_t ws_size,
                              hipStream_t stream)
{
    // ws layout: [partials 32KB | pad->64KB | fs 2MB | ft 2MB | Ws16 512KB | Wt16 512KB]
    const size_t WS_NEEDED = (64 << 10) + (4 << 20) + (1 << 20);
    if (ws_size < WS_NEEDED) return;   // readable failure instead of OOB fault

    const float* f_s = (const float*)d_in[0];
    const float* f_t = (const float*)d_in[1];
    const int*   y   = (const int*)d_in[2];
    const float* W_s = (const float*)d_in[3];
    const float* b_s = (const float*)d_in[4];
    const float* W_t = (const float*)d_in[5];
    const float* b_t = (const float*)d_in[6];
    float* out = (float*)d_out;

    char* ws = (char*)d_ws;
    double* partials = (double*)ws;                               // 32 KB
    half_t* fs   = (half_t*)(ws + (64 << 10));                    // 2 MB
    half_t* ft   = (half_t*)(ws + (64 << 10) + (2 << 20));        // 2 MB
    half_t* Ws16 = (half_t*)(ws + (64 << 10) + (4 << 20));        // 512 KB
    half_t* Wt16 = (half_t*)(ws + (64 << 10) + (4 << 20) + (512 << 10));

    cvt_w_kernel<<<dim3(256, 2), 256, 0, stream>>>(W_s, W_t, Ws16, Wt16);
    embed_kernel<<<dim3(256, 2), 256, 0, stream>>>(f_s, f_t, Ws16, Wt16, b_s, b_t, fs, ft);
    loss_kernel<<<dim3(64, 64), 256, 0, stream>>>(fs, ft, y, partials);
    finalize_kernel<<<1, 256, 0, stream>>>(partials, out);
    (void)in_sizes; (void)n_in; (void)out_size;
}